// Round 12
// baseline (8123.195 us; speedup 1.0000x reference)
//
#include <hip/hip_runtime.h>

#define TT 2048
#define HD 64

// One wave = one batch row, BOTH layers, zero barriers (R11 structure).
// Round 12 change: all 384 weight registers are PINNED via empty inline-asm
// "+v" constraints inside the loop, so the allocator cannot sink the weight
// loads into the loop (R11 failure: VGPR=212, weights re-loaded from L2 every
// step at 1 wave/SIMD -> latency-exposed, 4804us).
//
// Gate pre-scales folded into weights/biases:
//   sigmoid gates (i,f,o): t = -log2(e)*z   -> sigma(z) = rcp(1+exp2(t))
//   tanh gate (g):         t = -2*log2(e)*z -> tanh(z)  = 2*rcp(1+exp2(t)) - 1
#define SIC -1.4426950408889634f
#define SGC -2.8853900817779268f

#if __has_builtin(__builtin_amdgcn_exp2f)
#define EXP2F(x) __builtin_amdgcn_exp2f(x)
#else
#define EXP2F(x) __expf(0.69314718055994531f * (x))
#endif
#if __has_builtin(__builtin_amdgcn_rcpf)
#define RCPF(x) __builtin_amdgcn_rcpf(x)
#else
#define RCPF(x) (1.0f / (x))
#endif

__device__ __forceinline__ float rcp1p(float t) { return RCPF(1.0f + EXP2F(t)); }

typedef _Float16 v2h __attribute__((ext_vector_type(2)));

// v_dot2_f32_f16: 2 fp16 products + f32 accumulate in ONE VALU instr.
#if __has_builtin(__builtin_amdgcn_fdot2)
#define FDOT2(a, b, c) __builtin_amdgcn_fdot2((a), (b), (c), false)
#else
#define FDOT2(a, b, c) __fmaf_rn((float)(a)[1], (float)(b)[1], __fmaf_rn((float)(a)[0], (float)(b)[0], (c)))
#endif

static __device__ __forceinline__ v2h bch(float f) { return __builtin_bit_cast(v2h, f); }
static __device__ __forceinline__ v2h packw(float a, float b, float s) {
    v2h r; r[0] = (_Float16)(a * s); r[1] = (_Float16)(b * s); return r;
}

// Same-wave LDS ordering fence (write -> visible to own reads).
#define LGKM0() asm volatile("s_waitcnt lgkmcnt(0)" ::: "memory")

// ---- weight load: matrix-row P (one gate), 16 float4 -> 32 named v2h ----
#define LW1(P, k, sc) \
    const float4 P##q##k = P##p4[k]; \
    v2h P##_##k##a = packw(P##q##k.x, P##q##k.y, sc); \
    v2h P##_##k##b = packw(P##q##k.z, P##q##k.w, sc);

#define LOADW(P, g, sc, SRC) \
    const float4* P##p4 = (const float4*)((SRC) + ((g) * HD + lane) * HD); \
    LW1(P,0,sc)  LW1(P,1,sc)  LW1(P,2,sc)  LW1(P,3,sc)  \
    LW1(P,4,sc)  LW1(P,5,sc)  LW1(P,6,sc)  LW1(P,7,sc)  \
    LW1(P,8,sc)  LW1(P,9,sc)  LW1(P,10,sc) LW1(P,11,sc) \
    LW1(P,12,sc) LW1(P,13,sc) LW1(P,14,sc) LW1(P,15,sc)

// ---- register pinning: empty asm, "+v" makes each weight a loop-carried
// asm-defined value -> cannot be re-materialized from memory. 16 ops/asm. ----
#define PINLO(P) asm volatile("" : "+v"(P##_0a), "+v"(P##_0b), "+v"(P##_1a), "+v"(P##_1b), \
    "+v"(P##_2a), "+v"(P##_2b), "+v"(P##_3a), "+v"(P##_3b), "+v"(P##_4a), "+v"(P##_4b), \
    "+v"(P##_5a), "+v"(P##_5b), "+v"(P##_6a), "+v"(P##_6b), "+v"(P##_7a), "+v"(P##_7b))
#define PINHI(P) asm volatile("" : "+v"(P##_8a), "+v"(P##_8b), "+v"(P##_9a), "+v"(P##_9b), \
    "+v"(P##_10a), "+v"(P##_10b), "+v"(P##_11a), "+v"(P##_11b), "+v"(P##_12a), "+v"(P##_12b), \
    "+v"(P##_13a), "+v"(P##_13b), "+v"(P##_14a), "+v"(P##_14b), "+v"(P##_15a), "+v"(P##_15b))
#define PINM(P) PINLO(P); PINHI(P);

// ---- h broadcast read: 64B = 16 v2h pairs into named temps h0_..h15_ ----
#define LOADH(HP) \
    const float4 f0_ = *(const float4*)(HP); \
    const float4 f1_ = *(const float4*)((HP) + 16); \
    const float4 f2_ = *(const float4*)((HP) + 32); \
    const float4 f3_ = *(const float4*)((HP) + 48); \
    const v2h h0_  = bch(f0_.x), h1_  = bch(f0_.y), h2_  = bch(f0_.z), h3_  = bch(f0_.w), \
              h4_  = bch(f1_.x), h5_  = bch(f1_.y), h6_  = bch(f1_.z), h7_  = bch(f1_.w), \
              h8_  = bch(f2_.x), h9_  = bch(f2_.y), h10_ = bch(f2_.z), h11_ = bch(f2_.w), \
              h12_ = bch(f3_.x), h13_ = bch(f3_.y), h14_ = bch(f3_.z), h15_ = bch(f3_.w);

// ---- 16-pair dot for one gate: lo half uses weight ks 0..7, hi ks 8..15 ----
#define DOTLO(P, A) \
    A = FDOT2(P##_0a, h0_,  A); A = FDOT2(P##_0b, h1_,  A); \
    A = FDOT2(P##_1a, h2_,  A); A = FDOT2(P##_1b, h3_,  A); \
    A = FDOT2(P##_2a, h4_,  A); A = FDOT2(P##_2b, h5_,  A); \
    A = FDOT2(P##_3a, h6_,  A); A = FDOT2(P##_3b, h7_,  A); \
    A = FDOT2(P##_4a, h8_,  A); A = FDOT2(P##_4b, h9_,  A); \
    A = FDOT2(P##_5a, h10_, A); A = FDOT2(P##_5b, h11_, A); \
    A = FDOT2(P##_6a, h12_, A); A = FDOT2(P##_6b, h13_, A); \
    A = FDOT2(P##_7a, h14_, A); A = FDOT2(P##_7b, h15_, A);
#define DOTHI(P, A) \
    A = FDOT2(P##_8a,  h0_,  A); A = FDOT2(P##_8b,  h1_,  A); \
    A = FDOT2(P##_9a,  h2_,  A); A = FDOT2(P##_9b,  h3_,  A); \
    A = FDOT2(P##_10a, h4_,  A); A = FDOT2(P##_10b, h5_,  A); \
    A = FDOT2(P##_11a, h6_,  A); A = FDOT2(P##_11b, h7_,  A); \
    A = FDOT2(P##_12a, h8_,  A); A = FDOT2(P##_12b, h9_,  A); \
    A = FDOT2(P##_13a, h10_, A); A = FDOT2(P##_13b, h11_, A); \
    A = FDOT2(P##_14a, h12_, A); A = FDOT2(P##_14b, h13_, A); \
    A = FDOT2(P##_15a, h14_, A); A = FDOT2(P##_15b, h15_, A);

// Block = 256 threads = 4 independent waves (one row each), no __syncthreads
// in the loop. Grid 256 blocks -> 1024 waves = 1 wave per SIMD chip-wide.
// launch_bounds(256,1): 1 wave/EU -> VGPR budget 512 (weights need 384).
__global__ __launch_bounds__(256, 1)
void lstm2_kernel(const float* __restrict__ x,
                  const float* __restrict__ Wih0,
                  const float* __restrict__ Whh0,
                  const float* __restrict__ bih0,
                  const float* __restrict__ bhh0,
                  const float* __restrict__ Wih1,
                  const float* __restrict__ Whh1,
                  const float* __restrict__ bih1,
                  const float* __restrict__ bhh1,
                  const float* __restrict__ fcW,
                  const float* __restrict__ fcb,
                  float* __restrict__ out)
{
    __shared__ __align__(16) char arena[4 * 256];   // per-wave: h1[128B] + h2[128B]

    const int tid  = threadIdx.x;
    const int wid  = tid >> 6;
    const int lane = tid & 63;                      // unit j for both layers
    const int row  = blockIdx.x * 4 + wid;

    char* const hb  = arena + (wid << 8);           // h1 buffer
    char* const h2b = hb + 128;                     // h2 buffer

    // ---- weights: 384 named v2h registers, gate-prescaled at pack ----
    LOADW(w00, 0, SIC, Whh0) LOADW(w01, 1, SIC, Whh0)
    LOADW(w02, 2, SGC, Whh0) LOADW(w03, 3, SIC, Whh0)
    LOADW(wa0, 0, SIC, Wih1) LOADW(wa1, 1, SIC, Wih1)
    LOADW(wa2, 2, SGC, Wih1) LOADW(wa3, 3, SIC, Wih1)
    LOADW(wb0, 0, SIC, Whh1) LOADW(wb1, 1, SIC, Whh1)
    LOADW(wb2, 2, SGC, Whh1) LOADW(wb3, 3, SIC, Whh1)

    // biases / x-weights (f32, pre-scaled)
    const float b00 = (bih0[0 * HD + lane] + bhh0[0 * HD + lane]) * SIC;
    const float b01 = (bih0[1 * HD + lane] + bhh0[1 * HD + lane]) * SIC;
    const float b02 = (bih0[2 * HD + lane] + bhh0[2 * HD + lane]) * SGC;
    const float b03 = (bih0[3 * HD + lane] + bhh0[3 * HD + lane]) * SIC;
    const float wx0 = Wih0[0 * HD + lane] * SIC;
    const float wx1 = Wih0[1 * HD + lane] * SIC;
    const float wx2 = Wih0[2 * HD + lane] * SGC;
    const float wx3 = Wih0[3 * HD + lane] * SIC;
    const float b10 = (bih1[0 * HD + lane] + bhh1[0 * HD + lane]) * SIC;
    const float b11 = (bih1[1 * HD + lane] + bhh1[1 * HD + lane]) * SIC;
    const float b12 = (bih1[2 * HD + lane] + bhh1[2 * HD + lane]) * SGC;
    const float b13 = (bih1[3 * HD + lane] + bhh1[3 * HD + lane]) * SIC;
    const float fcwj = fcW[lane];

    // zero own h buffers (same-wave ordering via LGKM0)
    *(_Float16*)(hb  + (lane << 1)) = (_Float16)0.f;
    *(_Float16*)(h2b + (lane << 1)) = (_Float16)0.f;
    LGKM0();

    // x stream (all lanes same address -> cache broadcast)
    const float* xp = x + row * TT;
    float xv = xp[0], xn = xp[1];

    float c1 = 0.f, c2 = 0.f, hlast = 0.f;

#pragma unroll 1
    for (int i = 0; i < TT; ++i) {
        // pin all 384 weights: loop-carried asm defs, 0 instructions emitted
        PINM(w00) PINM(w01) PINM(w02) PINM(w03)
        PINM(wa0) PINM(wa1) PINM(wa2) PINM(wa3)
        PINM(wb0) PINM(wb1) PINM(wb2) PINM(wb3)

        const float xc = xv;
        xv = xn;
        xn = xp[(i + 2 < TT) ? (i + 2) : (TT - 1)];

        // ---- L0: gates = Whh0 . h1[i-1] + x*Wih0 + b ----
        float a0 = __fmaf_rn(xc, wx0, b00);
        float a1 = __fmaf_rn(xc, wx1, b01);
        float a2 = __fmaf_rn(xc, wx2, b02);
        float a3 = __fmaf_rn(xc, wx3, b03);
        { LOADH(hb)       DOTLO(w00, a0) DOTLO(w01, a1) DOTLO(w02, a2) DOTLO(w03, a3) }
        { LOADH(hb + 64)  DOTHI(w00, a0) DOTHI(w01, a1) DOTHI(w02, a2) DOTHI(w03, a3) }

        // ---- L1 h2-half early (independent of L0 act -> hides trans latency) ----
        float g0 = b10, g1 = b11, g2 = b12, g3 = b13;
        { LOADH(h2b)      DOTLO(wb0, g0) DOTLO(wb1, g1) DOTLO(wb2, g2) DOTLO(wb3, g3) }
        { LOADH(h2b + 64) DOTHI(wb0, g0) DOTHI(wb1, g1) DOTHI(wb2, g2) DOTHI(wb3, g3) }

        // ---- L0 activations -> h1[i] ----
        const float iv = rcp1p(a0);
        const float fv = rcp1p(a1);
        const float gv = __fmaf_rn(2.f, rcp1p(a2), -1.f);
        const float ov = rcp1p(a3);
        c1 = __fmaf_rn(fv, c1, iv * gv);
        const float h1n = ov * __fmaf_rn(2.f, rcp1p(c1 * SGC), -1.f);
        *(_Float16*)(hb + (lane << 1)) = (_Float16)h1n;
        LGKM0();                       // h1[i] visible to own reads

        // ---- L1 h1-half: Wih1 . h1[i] ----
        { LOADH(hb)       DOTLO(wa0, g0) DOTLO(wa1, g1) DOTLO(wa2, g2) DOTLO(wa3, g3) }
        { LOADH(hb + 64)  DOTHI(wa0, g0) DOTHI(wa1, g1) DOTHI(wa2, g2) DOTHI(wa3, g3) }

        // ---- L1 activations -> h2[i] ----
        const float i2 = rcp1p(g0);
        const float f2 = rcp1p(g1);
        const float g2v = __fmaf_rn(2.f, rcp1p(g2), -1.f);
        const float o2 = rcp1p(g3);
        c2 = __fmaf_rn(f2, c2, i2 * g2v);
        hlast = o2 * __fmaf_rn(2.f, rcp1p(c2 * SGC), -1.f);
        *(_Float16*)(h2b + (lane << 1)) = (_Float16)hlast;
        LGKM0();                       // h2[i] visible before next step's reads
    }

    // ---- FC: out[row] = sum_j h2[T-1][j] * fcW[j] + fcb (wave reduce) ----
    float s = hlast * fcwj;
    s += __shfl_xor(s, 1, 64);
    s += __shfl_xor(s, 2, 64);
    s += __shfl_xor(s, 4, 64);
    s += __shfl_xor(s, 8, 64);
    s += __shfl_xor(s, 16, 64);
    s += __shfl_xor(s, 32, 64);
    if (lane == 0) out[row] = s + fcb[0];
}

extern "C" void kernel_launch(void* const* d_in, const int* in_sizes, int n_in,
                              void* d_out, int out_size, void* d_ws, size_t ws_size,
                              hipStream_t stream) {
    const float* x    = (const float*)d_in[0];
    const float* Wih0 = (const float*)d_in[1];
    const float* Whh0 = (const float*)d_in[2];
    const float* bih0 = (const float*)d_in[3];
    const float* bhh0 = (const float*)d_in[4];
    const float* Wih1 = (const float*)d_in[5];
    const float* Whh1 = (const float*)d_in[6];
    const float* bih1 = (const float*)d_in[7];
    const float* bhh1 = (const float*)d_in[8];
    const float* fcW  = (const float*)d_in[9];
    const float* fcb  = (const float*)d_in[10];
    float* out = (float*)d_out;

    lstm2_kernel<<<256, 256, 0, stream>>>(x, Wih0, Whh0, bih0, bhh0,
                                          Wih1, Whh1, bih1, bhh1,
                                          fcW, fcb, out);
}

// Round 13
// 3004.874 us; speedup vs baseline: 2.7033x; 2.7033x over previous
//
#include <hip/hip_runtime.h>

#define TT 2048
#define HD 64

// Three specialized waves per batch row (block = 192 threads), lane j owns
// unit j. All three weight matrices are [4H,64] -> identical per-wave load:
//   wave0: Whh0  (L0 recurrence) -> produces h1[i]
//   wave1: Wih1  -> produces P1[i-1] = Wih1 . h1[i-1]  (f32 partial, LDS)
//   wave2: Whh1  -> combines P1[i-2] + P2(regs) + b -> h2[i-2]; then dots
//          Whh1 . h2[i-2] in-lane (same-wave lgkm only) -> P2 for next step.
// 128 v2h weight regs per wave (<=256 cap; R12 lesson: 384 is impossible).
// In-lane full-K dots: no cross-lane reduce, no idle lanes. ONE 3-wave
// barrier per step (vs 12-wave in R0-R10).
//
// LDS (per block): h1[2 parities][128B] @0/128; h2[128B] @256;
//                  P1[2 parities][4 gates][64 f32] @384/1408. Total 2432B.
#define H1B(par) ((par) * 128)
#define H2B 256
#define P1B(par) (384 + (par) * 1024)

// Gate pre-scales folded into weights/biases:
//   sigmoid gates (i,f,o): t = -log2(e)*z   -> sigma(z) = rcp(1+exp2(t))
//   tanh gate (g):         t = -2*log2(e)*z -> tanh(z)  = 2*rcp(1+exp2(t)) - 1
#define SIC -1.4426950408889634f
#define SGC -2.8853900817779268f

#if __has_builtin(__builtin_amdgcn_exp2f)
#define EXP2F(x) __builtin_amdgcn_exp2f(x)
#else
#define EXP2F(x) __expf(0.69314718055994531f * (x))
#endif
#if __has_builtin(__builtin_amdgcn_rcpf)
#define RCPF(x) __builtin_amdgcn_rcpf(x)
#else
#define RCPF(x) (1.0f / (x))
#endif

__device__ __forceinline__ float rcp1p(float t) { return RCPF(1.0f + EXP2F(t)); }

typedef _Float16 v2h __attribute__((ext_vector_type(2)));

#if __has_builtin(__builtin_amdgcn_fdot2)
#define FDOT2(a, b, c) __builtin_amdgcn_fdot2((a), (b), (c), false)
#else
#define FDOT2(a, b, c) __fmaf_rn((float)(a)[1], (float)(b)[1], __fmaf_rn((float)(a)[0], (float)(b)[0], (c)))
#endif

static __device__ __forceinline__ v2h bch(float f) { return __builtin_bit_cast(v2h, f); }
static __device__ __forceinline__ v2h packw(float a, float b, float s) {
    v2h r; r[0] = (_Float16)(a * s); r[1] = (_Float16)(b * s); return r;
}

// Same-wave LDS ordering fence (write -> visible to own reads).
#define LGKM0() asm volatile("s_waitcnt lgkmcnt(0)" ::: "memory")
// End-of-step 3-wave barrier (LDS-ordered; vmem prefetch rides across).
#define BARRIER() asm volatile("s_waitcnt lgkmcnt(0)\n\ts_barrier" ::: "memory")

// ---- weight load: one gate row, 16 float4 -> 32 named v2h (shared regs
// across roles: same names, role-dependent source pointer) ----
#define LW1(P, k, sc) \
    const float4 P##q##k = P##p4[k]; \
    v2h P##_##k##a = packw(P##q##k.x, P##q##k.y, sc); \
    v2h P##_##k##b = packw(P##q##k.z, P##q##k.w, sc);

#define LOADW(P, g, sc, SRC) \
    const float4* P##p4 = (const float4*)((SRC) + ((g) * HD + lane) * HD); \
    LW1(P,0,sc)  LW1(P,1,sc)  LW1(P,2,sc)  LW1(P,3,sc)  \
    LW1(P,4,sc)  LW1(P,5,sc)  LW1(P,6,sc)  LW1(P,7,sc)  \
    LW1(P,8,sc)  LW1(P,9,sc)  LW1(P,10,sc) LW1(P,11,sc) \
    LW1(P,12,sc) LW1(P,13,sc) LW1(P,14,sc) LW1(P,15,sc)

// ---- h broadcast read: 64B -> 16 v2h temps (braced scopes at use site) ----
#define LOADH(HP) \
    const float4 f0_ = *(const float4*)(HP); \
    const float4 f1_ = *(const float4*)((HP) + 16); \
    const float4 f2_ = *(const float4*)((HP) + 32); \
    const float4 f3_ = *(const float4*)((HP) + 48); \
    const v2h h0_  = bch(f0_.x), h1_  = bch(f0_.y), h2_  = bch(f0_.z), h3_  = bch(f0_.w), \
              h4_  = bch(f1_.x), h5_  = bch(f1_.y), h6_  = bch(f1_.z), h7_  = bch(f1_.w), \
              h8_  = bch(f2_.x), h9_  = bch(f2_.y), h10_ = bch(f2_.z), h11_ = bch(f2_.w), \
              h12_ = bch(f3_.x), h13_ = bch(f3_.y), h14_ = bch(f3_.z), h15_ = bch(f3_.w);

#define DOTLO(P, A) \
    A = FDOT2(P##_0a, h0_,  A); A = FDOT2(P##_0b, h1_,  A); \
    A = FDOT2(P##_1a, h2_,  A); A = FDOT2(P##_1b, h3_,  A); \
    A = FDOT2(P##_2a, h4_,  A); A = FDOT2(P##_2b, h5_,  A); \
    A = FDOT2(P##_3a, h6_,  A); A = FDOT2(P##_3b, h7_,  A); \
    A = FDOT2(P##_4a, h8_,  A); A = FDOT2(P##_4b, h9_,  A); \
    A = FDOT2(P##_5a, h10_, A); A = FDOT2(P##_5b, h11_, A); \
    A = FDOT2(P##_6a, h12_, A); A = FDOT2(P##_6b, h13_, A); \
    A = FDOT2(P##_7a, h14_, A); A = FDOT2(P##_7b, h15_, A);
#define DOTHI(P, A) \
    A = FDOT2(P##_8a,  h0_,  A); A = FDOT2(P##_8b,  h1_,  A); \
    A = FDOT2(P##_9a,  h2_,  A); A = FDOT2(P##_9b,  h3_,  A); \
    A = FDOT2(P##_10a, h4_,  A); A = FDOT2(P##_10b, h5_,  A); \
    A = FDOT2(P##_11a, h6_,  A); A = FDOT2(P##_11b, h7_,  A); \
    A = FDOT2(P##_12a, h8_,  A); A = FDOT2(P##_12b, h9_,  A); \
    A = FDOT2(P##_13a, h10_, A); A = FDOT2(P##_13b, h11_, A); \
    A = FDOT2(P##_14a, h12_, A); A = FDOT2(P##_14b, h13_, A); \
    A = FDOT2(P##_15a, h14_, A); A = FDOT2(P##_15b, h15_, A);

// Full 64-K dot of the 4 gates against a 128B h buffer.
#define DOT64(BUF, A0, A1, A2, A3) \
    { LOADH(BUF)      DOTLO(wg0, A0) DOTLO(wg1, A1) DOTLO(wg2, A2) DOTLO(wg3, A3) } \
    { LOADH((BUF)+64) DOTHI(wg0, A0) DOTHI(wg1, A1) DOTHI(wg2, A2) DOTHI(wg3, A3) }

// One pipeline step at compile-time parity PAR; I is the runtime step index.
// All guards are wave-uniform (wid and I).
#define STEP(I, PAR)                                                            \
{                                                                               \
    if (wid == 0) {                                                             \
        if ((I) < TT) {                                                         \
            const float xc = xv;                                                \
            xv = xn;                                                            \
            xn = xp[((I) + 2 < TT) ? ((I) + 2) : (TT - 1)];                     \
            float a0 = __fmaf_rn(xc, wx0, b0);                                  \
            float a1 = __fmaf_rn(xc, wx1, b1);                                  \
            float a2 = __fmaf_rn(xc, wx2, b2);                                  \
            float a3 = __fmaf_rn(xc, wx3, b3);                                  \
            DOT64(arena + H1B((PAR) ^ 1), a0, a1, a2, a3)                       \
            const float iv = rcp1p(a0);                                         \
            const float fv = rcp1p(a1);                                         \
            const float gv = __fmaf_rn(2.f, rcp1p(a2), -1.f);                   \
            const float ov = rcp1p(a3);                                         \
            c1 = __fmaf_rn(fv, c1, iv * gv);                                    \
            const float h1n = ov * __fmaf_rn(2.f, rcp1p(c1 * SGC), -1.f);       \
            *(_Float16*)(arena + H1B(PAR) + (lane << 1)) = (_Float16)h1n;       \
        }                                                                       \
    } else if (wid == 1) {                                                      \
        if ((I) >= 1 && (I) <= TT) {                                            \
            float a0 = 0.f, a1 = 0.f, a2 = 0.f, a3 = 0.f;                       \
            DOT64(arena + H1B((PAR) ^ 1), a0, a1, a2, a3)                       \
            *(float*)(arena + P1B((PAR) ^ 1) +   0 + (lane << 2)) = a0;         \
            *(float*)(arena + P1B((PAR) ^ 1) + 256 + (lane << 2)) = a1;         \
            *(float*)(arena + P1B((PAR) ^ 1) + 512 + (lane << 2)) = a2;         \
            *(float*)(arena + P1B((PAR) ^ 1) + 768 + (lane << 2)) = a3;         \
        }                                                                       \
    } else {                                                                    \
        if ((I) >= 2) {                                                         \
            const float q0 = *(const float*)(arena + P1B(PAR) +   0 + (lane << 2)); \
            const float q1 = *(const float*)(arena + P1B(PAR) + 256 + (lane << 2)); \
            const float q2 = *(const float*)(arena + P1B(PAR) + 512 + (lane << 2)); \
            const float q3 = *(const float*)(arena + P1B(PAR) + 768 + (lane << 2)); \
            const float iv = rcp1p(q0 + p20 + b0);                              \
            const float fv = rcp1p(q1 + p21 + b1);                              \
            const float gv = __fmaf_rn(2.f, rcp1p(q2 + p22 + b2), -1.f);        \
            const float ov = rcp1p(q3 + p23 + b3);                              \
            c1 = __fmaf_rn(fv, c1, iv * gv);                                    \
            hlast = ov * __fmaf_rn(2.f, rcp1p(c1 * SGC), -1.f);                 \
            *(_Float16*)(arena + H2B + (lane << 1)) = (_Float16)hlast;          \
            LGKM0();                                                            \
            if ((I) <= TT) {                                                    \
                p20 = 0.f; p21 = 0.f; p22 = 0.f; p23 = 0.f;                     \
                DOT64(arena + H2B, p20, p21, p22, p23)                          \
            }                                                                   \
        }                                                                       \
    }                                                                           \
    BARRIER();                                                                  \
}

// Block = 192 threads (3 waves, 1 row). Grid = 1024 blocks.
// launch_bounds(192,2): VGPR cap 256 -> no scratch by construction; at the
// expected ~170 VGPR the scheduler can still pack 3 waves/SIMD.
__global__ __launch_bounds__(192, 2)
void lstm2_kernel(const float* __restrict__ x,
                  const float* __restrict__ Wih0,
                  const float* __restrict__ Whh0,
                  const float* __restrict__ bih0,
                  const float* __restrict__ bhh0,
                  const float* __restrict__ Wih1,
                  const float* __restrict__ Whh1,
                  const float* __restrict__ bih1,
                  const float* __restrict__ bhh1,
                  const float* __restrict__ fcW,
                  const float* __restrict__ fcb,
                  float* __restrict__ out)
{
    __shared__ __align__(16) char arena[2432];

    const int tid  = threadIdx.x;
    const int wid  = tid >> 6;          // 0: L0   1: Wih1 partial   2: combiner
    const int lane = tid & 63;          // unit j
    const int row  = blockIdx.x;

    // ---- weights: 128 shared v2h regs; source matrix selected by role.
    // All three are [4H,64], so the addressing is identical. ----
    const float* Wsrc = (wid == 0) ? Whh0 : (wid == 1) ? Wih1 : Whh1;
    LOADW(wg0, 0, SIC, Wsrc)
    LOADW(wg1, 1, SIC, Wsrc)
    LOADW(wg2, 2, SGC, Wsrc)
    LOADW(wg3, 3, SIC, Wsrc)

    // role-dependent scalars (shared register slots)
    float b0 = 0.f, b1 = 0.f, b2 = 0.f, b3 = 0.f;
    float wx0 = 0.f, wx1 = 0.f, wx2 = 0.f, wx3 = 0.f;
    if (wid == 0) {
        b0 = (bih0[0 * HD + lane] + bhh0[0 * HD + lane]) * SIC;
        b1 = (bih0[1 * HD + lane] + bhh0[1 * HD + lane]) * SIC;
        b2 = (bih0[2 * HD + lane] + bhh0[2 * HD + lane]) * SGC;
        b3 = (bih0[3 * HD + lane] + bhh0[3 * HD + lane]) * SIC;
        wx0 = Wih0[0 * HD + lane] * SIC;
        wx1 = Wih0[1 * HD + lane] * SIC;
        wx2 = Wih0[2 * HD + lane] * SGC;
        wx3 = Wih0[3 * HD + lane] * SIC;
    } else if (wid == 2) {
        b0 = (bih1[0 * HD + lane] + bhh1[0 * HD + lane]) * SIC;
        b1 = (bih1[1 * HD + lane] + bhh1[1 * HD + lane]) * SIC;
        b2 = (bih1[2 * HD + lane] + bhh1[2 * HD + lane]) * SGC;
        b3 = (bih1[3 * HD + lane] + bhh1[3 * HD + lane]) * SIC;
    }
    const float fcwj = fcW[lane];

    // zero LDS state (h1 both parities by wave0; h2 by wave2)
    if (wid == 0) {
        *(_Float16*)(arena + H1B(0) + (lane << 1)) = (_Float16)0.f;
        *(_Float16*)(arena + H1B(1) + (lane << 1)) = (_Float16)0.f;
    } else if (wid == 2) {
        *(_Float16*)(arena + H2B + (lane << 1)) = (_Float16)0.f;
    }
    __syncthreads();

    // wave0 state: x stream (broadcast address), c1; wave2 reuses c1 for c2.
    const float* xp = x + row * TT;
    float xv = 0.f, xn = 0.f;
    if (wid == 0) { xv = xp[0]; xn = xp[1]; }
    float c1 = 0.f, hlast = 0.f;
    float p20 = 0.f, p21 = 0.f, p22 = 0.f, p23 = 0.f;   // wave2's Whh1.h2 partial

#pragma unroll 1
    for (int i = 0; i < TT + 2; i += 2) {
        STEP(i, 0)
        STEP(i + 1, 1)
    }

    // ---- FC: out[row] = sum_j h2[T-1][j] * fcW[j] + fcb (wave2 reduce) ----
    if (wid == 2) {
        float s = hlast * fcwj;
        s += __shfl_xor(s, 1, 64);
        s += __shfl_xor(s, 2, 64);
        s += __shfl_xor(s, 4, 64);
        s += __shfl_xor(s, 8, 64);
        s += __shfl_xor(s, 16, 64);
        s += __shfl_xor(s, 32, 64);
        if (lane == 0) out[row] = s + fcb[0];
    }
}

extern "C" void kernel_launch(void* const* d_in, const int* in_sizes, int n_in,
                              void* d_out, int out_size, void* d_ws, size_t ws_size,
                              hipStream_t stream) {
    const float* x    = (const float*)d_in[0];
    const float* Wih0 = (const float*)d_in[1];
    const float* Whh0 = (const float*)d_in[2];
    const float* bih0 = (const float*)d_in[3];
    const float* bhh0 = (const float*)d_in[4];
    const float* Wih1 = (const float*)d_in[5];
    const float* Whh1 = (const float*)d_in[6];
    const float* bih1 = (const float*)d_in[7];
    const float* bhh1 = (const float*)d_in[8];
    const float* fcW  = (const float*)d_in[9];
    const float* fcb  = (const float*)d_in[10];
    float* out = (float*)d_out;

    lstm2_kernel<<<1024, 192, 0, stream>>>(x, Wih0, Whh0, bih0, bhh0,
                                           Wih1, Whh1, bih1, bhh1,
                                           fcW, fcb, out);
}

// Round 16
// 2781.926 us; speedup vs baseline: 2.9200x; 1.0801x over previous
//
#include <hip/hip_runtime.h>

#define TT 2048
#define HD 64

// LDS arena, h stored as FP16 (c stays f32 in registers; only h is quantized):
//   h1 : [0, 1280)      parity p at p*640, row r at r*160, unit j at j*2
//   h2 : [1296, 2576)   same layout. H2_BASE ≡ 16 (mod 128): +4-bank skew so
//                       an L1 wave's 8 read addresses (ck0..7) cover all 32
//                       banks exactly once per ds_read_b128 (R8 had ≡64 → 16-bank
//                       skew → full 2-way conflict on every L1 read).
//   fcs: [2576, 3600)   f32 FC staging
#define H1_BASE 0
#define H2_BASE 1296
#define FCS_BASE 2576
#define PSTR 640
#define RSTR 160

// Gate pre-scales folded into (fp16) weights/biases at load time:
//   sigmoid gates (i,f,o): t = -log2(e)*z   -> sigma(z) = rcp(1+exp2(t))
//   tanh gate (g):         t = -2*log2(e)*z -> tanh(z)  = 2*rcp(1+exp2(t)) - 1
#define SIC -1.4426950408889634f
#define SGC -2.8853900817779268f

#if __has_builtin(__builtin_amdgcn_exp2f)
#define EXP2F(x) __builtin_amdgcn_exp2f(x)
#else
#define EXP2F(x) __expf(0.69314718055994531f * (x))
#endif
#if __has_builtin(__builtin_amdgcn_rcpf)
#define RCPF(x) __builtin_amdgcn_rcpf(x)
#else
#define RCPF(x) (1.0f / (x))
#endif

__device__ __forceinline__ float rcp1p(float t) { return RCPF(1.0f + EXP2F(t)); }

typedef _Float16 v2h __attribute__((ext_vector_type(2)));

// v_dot2_f32_f16: 2 fp16 products + f32 accumulate in ONE VALU instr.
#if __has_builtin(__builtin_amdgcn_fdot2)
#define FDOT2(a, b, c) __builtin_amdgcn_fdot2((a), (b), (c), false)
#else
#define FDOT2(a, b, c) __fmaf_rn((float)(a)[1], (float)(b)[1], __fmaf_rn((float)(a)[0], (float)(b)[0], (c)))
#endif

static __device__ __forceinline__ v2h bch(float f) { return __builtin_bit_cast(v2h, f); }
static __device__ __forceinline__ v2h packw(float a, float b, float s) {
    v2h r; r[0] = (_Float16)(a * s); r[1] = (_Float16)(b * s); return r;
}

// pure DPP cross-lane move (stays OFF the LDS pipe).
// Receiver lane i gets in[(i-n)&15] for row_ror:n.
// 0xB1 = quad_perm xor1, 0x4E = quad_perm xor2,
// 0x12C = row_ror:12 -> out[i] = in[(i-12)&15] = in[(i+4)&15]  (verified R5).
template<int CTRL>
__device__ __forceinline__ float dpp_get(float v) {
    return __int_as_float(__builtin_amdgcn_update_dpp(0, __float_as_int(v), CTRL, 0xF, 0xF, true));
}

// Hot-loop barrier: order LDS ops only; let vmem/scalar prefetches ride across.
#define BARRIER() asm volatile("s_waitcnt lgkmcnt(0)\n\ts_barrier" ::: "memory")

// 16-K dot for one gate: 8 fdot2, first seeds from c=0 (inline const, no mov).
#define GDOT8I(acc, W) \
    acc = FDOT2(W##0, h0_, 0.0f); \
    acc = FDOT2(W##1, h1_, acc);  \
    acc = FDOT2(W##2, h2_, acc);  \
    acc = FDOT2(W##3, h3_, acc);  \
    acc = FDOT2(W##4, h4_, acc);  \
    acc = FDOT2(W##5, h5_, acc);  \
    acc = FDOT2(W##6, h6_, acc);  \
    acc = FDOT2(W##7, h7_, acc);

// One h-row (16 fp16 = 32B) in TWO ds_read_b128; 4 gates = 32 fdot2.
// P = pointer-set prefix (pe/po), parity baked in -> reg+imm addressing.
#define ROWDOTH(P, ROFF, A0, A1, A2, A3) { \
    const float4 f0_ = *(const float4*)(P##0 + (ROFF)); \
    const float4 f1_ = *(const float4*)(P##1 + (ROFF)); \
    const v2h h0_ = bch(f0_.x), h1_ = bch(f0_.y), h2_ = bch(f0_.z), h3_ = bch(f0_.w); \
    const v2h h4_ = bch(f1_.x), h5_ = bch(f1_.y), h6_ = bch(f1_.z), h7_ = bch(f1_.w); \
    GDOT8I(A0, wA) \
    GDOT8I(A1, wB) \
    GDOT8I(A2, wC) \
    GDOT8I(A3, wD) }

// Packed row-select quad reduction: lane q (q = rk) ends with the full quad
// sum of row q's partials. 6 cndmask + 3 dpp-adds.
#define QRED(e, r0, r1, r2, r3) \
    float e; { \
        float x_ = q1 ? (r1) : (r0); float y_ = q1 ? (r0) : (r1); \
        x_ += dpp_get<0xB1>(y_); \
        float z_ = q1 ? (r3) : (r2); float w_ = q1 ? (r2) : (r3); \
        z_ += dpp_get<0xB1>(w_); \
        float u_ = q2 ? z_ : x_; float v_ = q2 ? x_ : z_; \
        e = u_ + dpp_get<0x4E>(v_); \
    }

// One pipelined timestep. P = pointer set (pe even / po odd), X = x register
// (xa even / xb odd; each L0 lane streams only ITS row rk's x stream),
// L0WOFF/L1WOFF = parity write byte offsets (0 / PSTR), DO_L1 gates L1,
// XNI = x prefetch index. Bias + x*Wih inject POST-QRED (once per lane).
#define STEP(P, X, L0WOFF, L1WOFF, DO_L1, XNI)                                  \
{                                                                               \
    float xv = 0.f;                                                             \
    if (isL0) {                                                                 \
        xv = X;                                                                 \
        const int xi_ = (XNI) < TT ? (XNI) : (TT - 1);                          \
        X = xps[xi_];                                                           \
    }                                                                           \
    float a00, a01, a02, a03, a10, a11, a12, a13;                               \
    float a20, a21, a22, a23, a30, a31, a32, a33;                               \
    ROWDOTH(P, 0 * RSTR, a00, a01, a02, a03)                                    \
    ROWDOTH(P, 1 * RSTR, a10, a11, a12, a13)                                    \
    ROWDOTH(P, 2 * RSTR, a20, a21, a22, a23)                                    \
    ROWDOTH(P, 3 * RSTR, a30, a31, a32, a33)                                    \
    QRED(e0_, a00, a10, a20, a30)                                               \
    QRED(e1_, a01, a11, a21, a31)                                               \
    QRED(e2_, a02, a12, a22, a32)                                               \
    QRED(e3_, a03, a13, a23, a33)                                               \
    if (isL0) {                                                                 \
        const float iv = rcp1p(__fmaf_rn(xv, wxm0, bgm0) + e0_);                \
        const float fv = rcp1p(__fmaf_rn(xv, wxm1, bgm1) + e1_);                \
        const float gv = __fmaf_rn(2.f, rcp1p(__fmaf_rn(xv, wxm2, bgm2) + e2_), -1.f); \
        const float ov = rcp1p(__fmaf_rn(xv, wxm3, bgm3) + e3_);                \
        cc = __fmaf_rn(fv, cc, iv * gv);                                        \
        const float th = __fmaf_rn(2.f, rcp1p(cc * SGC), -1.f);                 \
        *(_Float16*)(wraddr + (L0WOFF)) = (_Float16)(ov * th);                  \
    } else {                                                                    \
        /* cross-half (ck vs ck+4) combine: row_ror:12 -> in[(i+4)&15].         \
           Lanes ck>=4 receive junk but never consume (ck<4 gate). */           \
        e0_ += dpp_get<0x12C>(e0_);                                             \
        e1_ += dpp_get<0x12C>(e1_);                                             \
        e2_ += dpp_get<0x12C>(e2_);                                             \
        e3_ += dpp_get<0x12C>(e3_);                                             \
        if ((DO_L1) && ck < 4) {                                                \
            const float iv = rcp1p(e0_ + bgm0);                                 \
            const float fv = rcp1p(e1_ + bgm1);                                 \
            const float gv = __fmaf_rn(2.f, rcp1p(e2_ + bgm2), -1.f);           \
            const float ov = rcp1p(e3_ + bgm3);                                 \
            cc = __fmaf_rn(fv, cc, iv * gv);                                    \
            hlast = ov * __fmaf_rn(2.f, rcp1p(cc * SGC), -1.f);                 \
            *(_Float16*)(wraddr + (L1WOFF)) = (_Float16)hlast;                  \
        }                                                                       \
    }                                                                           \
    BARRIER();                                                                  \
}

// Block = 768 threads, 4 batch rows per block, 1 block/CU.
//   waves 0-3  (tid 0..255):   layer0.  j=tid>>2, ck=tid&3  (16-wide K chunk of 64)
//   waves 4-11 (tid 256..767): layer1.  p=tid-256, j=p>>3, ck=p&7 (chunk of K=128=[h1|h2])
// Pipeline: iter i does layer0 step i and layer1 step i-1; ONE barrier per iter.
// h crosses steps through LDS as FP16 (c never quantized); dots use
// v_dot2_f32_f16 -> LDS load (8 ds_read_b128/lane) and dot issue (128/lane)
// are HALF the f32 version's. H2_BASE bank-skewed so L1 reads are conflict-free.
__global__ __launch_bounds__(768, 3)
void lstm2_kernel(const float* __restrict__ x,
                  const float* __restrict__ Wih0,
                  const float* __restrict__ Whh0,
                  const float* __restrict__ bih0,
                  const float* __restrict__ bhh0,
                  const float* __restrict__ Wih1,
                  const float* __restrict__ Whh1,
                  const float* __restrict__ bih1,
                  const float* __restrict__ bhh1,
                  const float* __restrict__ fcW,
                  const float* __restrict__ fcb,
                  float* __restrict__ out)
{
    __shared__ __align__(16) float arena_f[912];
    char* const arena = (char*)arena_f;

    const int tid  = threadIdx.x;
    const int row0 = blockIdx.x * 4;

    const bool isL0 = (tid < 256);
    const int  p    = isL0 ? tid : (tid - 256);
    const int  j    = isL0 ? (p >> 2) : (p >> 3);
    const int  ck   = isL0 ? (p & 3)  : (p & 7);
    const int  ckk  = (ck < 4) ? ck : (ck - 4);
    const int  rk   = ck & 3;                      // this lane's output row
    const bool q1   = (rk & 1) != 0;
    const bool q2   = (rk & 2) != 0;

    // ---- weights: 32 packed v2h registers (fp16), gate-prescaled at pack ----
    const float* Wsrc;
    if (isL0)        Wsrc = Whh0;
    else if (ck < 4) Wsrc = Wih1;
    else             Wsrc = Whh1;
    const int kbase = 16 * ckk;
    const float* Wg0 = Wsrc + (0 * HD + j) * HD + kbase;
    const float* Wg1 = Wsrc + (1 * HD + j) * HD + kbase;
    const float* Wg2 = Wsrc + (2 * HD + j) * HD + kbase;
    const float* Wg3 = Wsrc + (3 * HD + j) * HD + kbase;
    const v2h wA0 = packw(Wg0[0],  Wg0[1],  SIC), wA1 = packw(Wg0[2],  Wg0[3],  SIC),
              wA2 = packw(Wg0[4],  Wg0[5],  SIC), wA3 = packw(Wg0[6],  Wg0[7],  SIC),
              wA4 = packw(Wg0[8],  Wg0[9],  SIC), wA5 = packw(Wg0[10], Wg0[11], SIC),
              wA6 = packw(Wg0[12], Wg0[13], SIC), wA7 = packw(Wg0[14], Wg0[15], SIC);
    const v2h wB0 = packw(Wg1[0],  Wg1[1],  SIC), wB1 = packw(Wg1[2],  Wg1[3],  SIC),
              wB2 = packw(Wg1[4],  Wg1[5],  SIC), wB3 = packw(Wg1[6],  Wg1[7],  SIC),
              wB4 = packw(Wg1[8],  Wg1[9],  SIC), wB5 = packw(Wg1[10], Wg1[11], SIC),
              wB6 = packw(Wg1[12], Wg1[13], SIC), wB7 = packw(Wg1[14], Wg1[15], SIC);
    const v2h wC0 = packw(Wg2[0],  Wg2[1],  SGC), wC1 = packw(Wg2[2],  Wg2[3],  SGC),
              wC2 = packw(Wg2[4],  Wg2[5],  SGC), wC3 = packw(Wg2[6],  Wg2[7],  SGC),
              wC4 = packw(Wg2[8],  Wg2[9],  SGC), wC5 = packw(Wg2[10], Wg2[11], SGC),
              wC6 = packw(Wg2[12], Wg2[13], SGC), wC7 = packw(Wg2[14], Wg2[15], SGC);
    const v2h wD0 = packw(Wg3[0],  Wg3[1],  SIC), wD1 = packw(Wg3[2],  Wg3[3],  SIC),
              wD2 = packw(Wg3[4],  Wg3[5],  SIC), wD3 = packw(Wg3[6],  Wg3[7],  SIC),
              wD4 = packw(Wg3[8],  Wg3[9],  SIC), wD5 = packw(Wg3[10], Wg3[11], SIC),
              wD6 = packw(Wg3[12], Wg3[13], SIC), wD7 = packw(Wg3[14], Wg3[15], SIC);

    // Biases / x-weights, f32, pre-scaled, UNMASKED (added once, post-QRED).
    float bgm0, bgm1, bgm2, bgm3, wxm0 = 0.f, wxm1 = 0.f, wxm2 = 0.f, wxm3 = 0.f;
    if (isL0) {
        bgm0 = (bih0[0*HD+j] + bhh0[0*HD+j]) * SIC;
        bgm1 = (bih0[1*HD+j] + bhh0[1*HD+j]) * SIC;
        bgm2 = (bih0[2*HD+j] + bhh0[2*HD+j]) * SGC;
        bgm3 = (bih0[3*HD+j] + bhh0[3*HD+j]) * SIC;
        wxm0 = Wih0[0*HD+j] * SIC;
        wxm1 = Wih0[1*HD+j] * SIC;
        wxm2 = Wih0[2*HD+j] * SGC;
        wxm3 = Wih0[3*HD+j] * SIC;
    } else {
        bgm0 = (bih1[0*HD+j] + bhh1[0*HD+j]) * SIC;
        bgm1 = (bih1[1*HD+j] + bhh1[1*HD+j]) * SIC;
        bgm2 = (bih1[2*HD+j] + bhh1[2*HD+j]) * SGC;
        bgm3 = (bih1[3*HD+j] + bhh1[3*HD+j]) * SIC;
    }

    // LDS read pointers: parity baked into TWO sets; each row read is 2
    // ds_read_b128 at reg+imm (row offsets 0/160/320/480).
    const int rdBase = (ck < 4) ? H1_BASE : H2_BASE;   // isL0 has ck<4
    const int rdPh   = (ck < 4) ? 1 : 0;               // h1 readers: (i+1)&1; h2: i&1
    const int coff   = ckk * 32;

    const char* pe0 = arena + rdBase + rdPh * PSTR + coff;
    const char* pe1 = pe0 + 16;
    const char* po0 = arena + rdBase + (rdPh ^ 1) * PSTR + coff;
    const char* po1 = po0 + 16;

    // writers: lane's row rk, unit j, fp16 element
    char* const wraddr = arena + (isL0 ? H1_BASE : H2_BASE) + rk * RSTR + (j << 1);

    // zero h1+h2 (both parities; [0, 2576) covers all h storage)
    for (int z = tid; z < 644; z += 768)
        *(float*)(arena + 4 * z) = 0.f;

    // Each L0 lane streams only ITS row's x (lane rk -> batch row row0+rk).
    const float* xps = x + (row0 + rk) * TT;
    float xa = 0.f, xb = 0.f;
    if (isL0) { xa = xps[0]; xb = xps[1]; }

    const float fcwj = fcW[j];
    float cc = 0.f, hlast = 0.f;

    __syncthreads();

    STEP(pe, xa, 0, PSTR, false, 2)      // i = 0: L0 only
    STEP(po, xb, PSTR, 0, true, 3)       // i = 1: first L1 step (step 0)
#pragma unroll 1
    for (int i = 2; i < TT; i += 2) {
        STEP(pe, xa, 0, PSTR, true, i + 2)
        STEP(po, xb, PSTR, 0, true, i + 3)
    }
    // tail i = 2048: layer1 step 2047 only (no L0, no h2 store needed)
    if (!isL0) {
        float a00, a01, a02, a03, a10, a11, a12, a13;
        float a20, a21, a22, a23, a30, a31, a32, a33;
        ROWDOTH(pe, 0 * RSTR, a00, a01, a02, a03)
        ROWDOTH(pe, 1 * RSTR, a10, a11, a12, a13)
        ROWDOTH(pe, 2 * RSTR, a20, a21, a22, a23)
        ROWDOTH(pe, 3 * RSTR, a30, a31, a32, a33)
        QRED(e0_, a00, a10, a20, a30)
        QRED(e1_, a01, a11, a21, a31)
        QRED(e2_, a02, a12, a22, a32)
        QRED(e3_, a03, a13, a23, a33)
        e0_ += dpp_get<0x12C>(e0_);
        e1_ += dpp_get<0x12C>(e1_);
        e2_ += dpp_get<0x12C>(e2_);
        e3_ += dpp_get<0x12C>(e3_);
        if (ck < 4) {
            const float iv = rcp1p(e0_ + bgm0);
            const float fv = rcp1p(e1_ + bgm1);
            const float gv = __fmaf_rn(2.f, rcp1p(e2_ + bgm2), -1.f);
            const float ov = rcp1p(e3_ + bgm3);
            cc = __fmaf_rn(fv, cc, iv * gv);
            hlast = ov * __fmaf_rn(2.f, rcp1p(cc * SGC), -1.f);
        }
    }
    __syncthreads();

    // ---- FC: out[row] = sum_j h2[T-1][row][j] * fcW[j] + fcb (f32 path) ----
    if (!isL0 && ck < 4)
        *(float*)(arena + FCS_BASE + ((rk * HD + j) << 2)) = hlast * fcwj;
    __syncthreads();

    if (tid < 64) {
        const int r = tid >> 4, seg = tid & 15;
        const float4 v = ((const float4*)(arena + FCS_BASE))[r * 16 + seg];
        float s = (v.x + v.y) + (v.z + v.w);
        s += __shfl_xor(s, 1, 64);
        s += __shfl_xor(s, 2, 64);
        s += __shfl_xor(s, 4, 64);
        s += __shfl_xor(s, 8, 64);
        if (seg == 0) out[row0 + r] = s + fcb[0];
    }
}

extern "C" void kernel_launch(void* const* d_in, const int* in_sizes, int n_in,
                              void* d_out, int out_size, void* d_ws, size_t ws_size,
                              hipStream_t stream) {
    const float* x    = (const float*)d_in[0];
    const float* Wih0 = (const float*)d_in[1];
    const float* Whh0 = (const float*)d_in[2];
    const float* bih0 = (const float*)d_in[3];
    const float* bhh0 = (const float*)d_in[4];
    const float* Wih1 = (const float*)d_in[5];
    const float* Whh1 = (const float*)d_in[6];
    const float* bih1 = (const float*)d_in[7];
    const float* bhh1 = (const float*)d_in[8];
    const float* fcW  = (const float*)d_in[9];
    const float* fcb  = (const float*)d_in[10];
    float* out = (float*)d_out;

    lstm2_kernel<<<256, 768, 0, stream>>>(x, Wih0, Whh0, bih0, bhh0,
                                          Wih1, Whh1, bih1, bhh1,
                                          fcW, fcb, out);
}